// Round 2
// baseline (857.233 us; speedup 1.0000x reference)
//
#include <hip/hip_runtime.h>

#define BATCH 2048
#define TSEQ 512
#define FUT 64
#define TOUT (TSEQ + FUT)   // 576
#define HID 50
#define ROWS_PER_BLK 4      // 4 waves per block, 1 row per wave

__device__ __forceinline__ float rcp_f(float x) {
#if __has_builtin(__builtin_amdgcn_rcpf)
  return __builtin_amdgcn_rcpf(x);   // v_rcp_f32, ~1 ulp
#else
  return 1.f / x;
#endif
}
__device__ __forceinline__ float sigm(float x) {
  return rcp_f(1.f + __expf(-x));            // stable both tails
}
__device__ __forceinline__ float tanh_f(float x) {
  return 1.f - 2.f * rcp_f(__expf(2.f * x) + 1.f);  // inf-safe
}
__device__ __forceinline__ float rdlane(float v, int m) {
  return __uint_as_float(__builtin_amdgcn_readlane(__float_as_uint(v), m));
}

__global__ __launch_bounds__(256, 2) void lstm_seq_kernel(
    const float* __restrict__ x,      // [B, T]
    const float* __restrict__ W_ih,   // [200, 1]
    const float* __restrict__ W_hh,   // [200, 50]
    const float* __restrict__ b_ih,   // [200]
    const float* __restrict__ b_hh,   // [200]
    const float* __restrict__ W_out,  // [1, 50]
    const float* __restrict__ b_out,  // [1]
    float* __restrict__ out)          // [B, 576]
{
  __shared__ float sW[4 * HID * HID];        // 40 KB: W_hh staged once
  __shared__ float sx[ROWS_PER_BLK][TSEQ];   // 8 KB: this block's input rows

  const int tid  = threadIdx.x;
  const int wv   = tid >> 6;
  const int lane = tid & 63;
  const int row  = blockIdx.x * ROWS_PER_BLK + wv;

  // one-time coalesced staging
  for (int i = tid; i < 4 * HID * HID; i += 256) sW[i] = W_hh[i];
  for (int i = lane; i < TSEQ; i += 64) sx[wv][i] = x[row * TSEQ + i];
  __syncthreads();

  const bool act = (lane < HID);
  const int  kk  = act ? lane : 0;   // clamp for inactive lanes (masked later)

  // W_hh rows {k, k+50, k+100, k+150} live in registers (200 VGPRs/lane)
  float w_i[HID], w_f[HID], w_g[HID], w_o[HID];
  #pragma unroll
  for (int m = 0; m < HID; ++m) {
    w_i[m] = sW[(0 * HID + kk) * HID + m];
    w_f[m] = sW[(1 * HID + kk) * HID + m];
    w_g[m] = sW[(2 * HID + kk) * HID + m];
    w_o[m] = sW[(3 * HID + kk) * HID + m];
  }
  const float bi = b_ih[0 * HID + kk] + b_hh[0 * HID + kk];
  const float bf = b_ih[1 * HID + kk] + b_hh[1 * HID + kk];
  const float bg = b_ih[2 * HID + kk] + b_hh[2 * HID + kk];
  const float bo = b_ih[3 * HID + kk] + b_hh[3 * HID + kk];
  const float wxi = W_ih[0 * HID + kk];
  const float wxf = W_ih[1 * HID + kk];
  const float wxg = W_ih[2 * HID + kk];
  const float wxo = W_ih[3 * HID + kk];
  const float wout = act ? W_out[kk] : 0.f;
  const float bout = b_out[0];

  float h = 0.f, c = 0.f, oprev = 0.f;
  float* orow = out + (size_t)row * TOUT;

  auto step = [&](float xv, int t) {
    float ai = fmaf(xv, wxi, bi);
    float af = fmaf(xv, wxf, bf);
    float ag = fmaf(xv, wxg, bg);
    float ao = fmaf(xv, wxo, bo);
    #pragma unroll
    for (int m = 0; m < HID; ++m) {
      float hm = rdlane(h, m);          // v_readlane: h[m] is wave-uniform
      ai = fmaf(w_i[m], hm, ai);
      af = fmaf(w_f[m], hm, af);
      ag = fmaf(w_g[m], hm, ag);
      ao = fmaf(w_o[m], hm, ao);
    }
    float gi = sigm(ai), gf = sigm(af), gg = tanh_f(ag), go = sigm(ao);
    c = fmaf(gf, c, gi * gg);
    float hn = go * tanh_f(c);
    h = act ? hn : 0.f;                 // inactive lanes keep h = 0
    // out_t = sum_k h[k]*W_out[k] + b_out : 64-lane butterfly (idle lanes add 0)
    float p = h * wout;
    p += __shfl_xor(p, 1);
    p += __shfl_xor(p, 2);
    p += __shfl_xor(p, 4);
    p += __shfl_xor(p, 8);
    p += __shfl_xor(p, 16);
    p += __shfl_xor(p, 32);
    float ot = p + bout;
    if (lane == 0) orow[t] = ot;
    oprev = ot;                         // next input during the future phase
  };

  for (int t = 0; t < TSEQ; ++t) step(sx[wv][t], t);       // teacher-forced
  for (int t = TSEQ; t < TOUT; ++t) step(oprev, t);        // autoregressive
}

extern "C" void kernel_launch(void* const* d_in, const int* in_sizes, int n_in,
                              void* d_out, int out_size, void* d_ws, size_t ws_size,
                              hipStream_t stream) {
  const float* x     = (const float*)d_in[0];
  const float* W_ih  = (const float*)d_in[1];
  const float* W_hh  = (const float*)d_in[2];
  const float* b_ih  = (const float*)d_in[3];
  const float* b_hh  = (const float*)d_in[4];
  const float* W_out = (const float*)d_in[5];
  const float* b_out = (const float*)d_in[6];
  float* out = (float*)d_out;

  lstm_seq_kernel<<<BATCH / ROWS_PER_BLK, 256, 0, stream>>>(
      x, W_ih, W_hh, b_ih, b_hh, W_out, b_out, out);
}

// Round 5
// 577.676 us; speedup vs baseline: 1.4839x; 1.4839x over previous
//
#include <hip/hip_runtime.h>

typedef float v2f __attribute__((ext_vector_type(2)));
typedef float v4f __attribute__((ext_vector_type(4)));

#define BATCH 2048
#define TSEQ 512
#define FUT 64
#define TOUT (TSEQ + FUT)   // 576
#define HID 50
#define RPB 4               // 4 waves per block, 1 batch row per wave

__device__ __forceinline__ float rcp_f(float x) { return __builtin_amdgcn_rcpf(x); }
__device__ __forceinline__ float sigm(float x)  { return rcp_f(1.f + __expf(-x)); }
__device__ __forceinline__ float tanh_f(float x){ return 1.f - 2.f * rcp_f(__expf(2.f * x) + 1.f); }

// packed 2xf32 FMA: acc = a*b + acc  (VOP3P v_pk_fma_f32, 64-bit operands)
__device__ __forceinline__ void pkfma(v2f& acc, v2f a, v2f b) {
  asm("v_pk_fma_f32 %0, %1, %2, %0" : "+v"(acc) : "v"(a), "v"(b));
}

__global__ __launch_bounds__(256, 2) void lstm_seq_kernel(
    const float* __restrict__ x,      // [B, T]
    const float* __restrict__ W_ih,   // [200, 1]
    const float* __restrict__ W_hh,   // [200, 50]
    const float* __restrict__ b_ih,   // [200]
    const float* __restrict__ b_hh,   // [200]
    const float* __restrict__ W_out,  // [1, 50]
    const float* __restrict__ b_out,  // [1]
    float* __restrict__ out)          // [B, 576]
{
  __shared__ float sW[4 * HID * HID];       // 40 KB, staged once, read once
  __shared__ float sx[RPB][TSEQ];           // 8 KB input rows
  __shared__ float sH[RPB][64];             // per-wave h broadcast buffer

  const int tid  = threadIdx.x;
  const int wv   = tid >> 6;
  const int lane = tid & 63;
  const int row  = blockIdx.x * RPB + wv;

  for (int i = tid; i < 4 * HID * HID; i += 256) sW[i] = W_hh[i];
  for (int i = lane; i < TSEQ; i += 64) sx[wv][i] = x[row * TSEQ + i];
  sH[wv][lane] = 0.f;
  __syncthreads();

  const bool act = (lane < HID);
  const int  kk  = act ? lane : 0;

  // weights as K-pairs: w?[j] = {W[g*50+kk][2j], W[g*50+kk][2j+1]}  (200 VGPRs)
  v2f wi[25], wf[25], wg[25], wo[25];
  {
    const v2f* r0 = (const v2f*)&sW[(0 * HID + kk) * HID];
    const v2f* r1 = (const v2f*)&sW[(1 * HID + kk) * HID];
    const v2f* r2 = (const v2f*)&sW[(2 * HID + kk) * HID];
    const v2f* r3 = (const v2f*)&sW[(3 * HID + kk) * HID];
    #pragma unroll
    for (int j = 0; j < 25; ++j) { wi[j] = r0[j]; wf[j] = r1[j]; wg[j] = r2[j]; wo[j] = r3[j]; }
  }
  const float bi = b_ih[0 * HID + kk] + b_hh[0 * HID + kk];
  const float bf = b_ih[1 * HID + kk] + b_hh[1 * HID + kk];
  const float bg = b_ih[2 * HID + kk] + b_hh[2 * HID + kk];
  const float bo = b_ih[3 * HID + kk] + b_hh[3 * HID + kk];
  const float wxi = W_ih[0 * HID + kk];
  const float wxf = W_ih[1 * HID + kk];
  const float wxg = W_ih[2 * HID + kk];
  const float wxo = W_ih[3 * HID + kk];
  const float wout = act ? W_out[kk] : 0.f;
  const float bout = b_out[0];

  float h = 0.f, c = 0.f, oprev = 0.f;
  float* orow = out + (size_t)row * TOUT;
  const v4f* sH4 = (const v4f*)sH[wv];
  const v2f* sH2 = (const v2f*)sH[wv];

  auto step = [&](float xv, int t) {
    sH[wv][lane] = h;                      // wave-private; compiler inserts lgkmcnt
    v2f ai2 = {fmaf(xv, wxi, bi), 0.f};
    v2f af2 = {fmaf(xv, wxf, bf), 0.f};
    v2f ag2 = {fmaf(xv, wxg, bg), 0.f};
    v2f ao2 = {fmaf(xv, wxo, bo), 0.f};
    #pragma unroll
    for (int q = 0; q < 12; ++q) {         // m = 0..47, uniform b128 reads (broadcast)
      v4f h4 = sH4[q];
      v2f ha = {h4.x, h4.y}, hb = {h4.z, h4.w};
      pkfma(ai2, wi[2 * q], ha); pkfma(ai2, wi[2 * q + 1], hb);
      pkfma(af2, wf[2 * q], ha); pkfma(af2, wf[2 * q + 1], hb);
      pkfma(ag2, wg[2 * q], ha); pkfma(ag2, wg[2 * q + 1], hb);
      pkfma(ao2, wo[2 * q], ha); pkfma(ao2, wo[2 * q + 1], hb);
    }
    {                                      // m = 48,49
      v2f ht = sH2[24];
      pkfma(ai2, wi[24], ht); pkfma(af2, wf[24], ht);
      pkfma(ag2, wg[24], ht); pkfma(ao2, wo[24], ht);
    }
    float gi = sigm(ai2.x + ai2.y);
    float gf = sigm(af2.x + af2.y);
    float gg = tanh_f(ag2.x + ag2.y);
    float go = sigm(ao2.x + ao2.y);
    c = fmaf(gf, c, gi * gg);
    float hn = go * tanh_f(c);
    h = act ? hn : 0.f;
    float p = h * wout;                    // out_t = sum h[k] W_out[k] + b
    p += __shfl_xor(p, 1);
    p += __shfl_xor(p, 2);
    p += __shfl_xor(p, 4);
    p += __shfl_xor(p, 8);
    p += __shfl_xor(p, 16);
    p += __shfl_xor(p, 32);
    float ot = p + bout;
    if (lane == 0) orow[t] = ot;
    oprev = ot;
  };

  #pragma unroll 1
  for (int t = 0; t < TSEQ; ++t) step(sx[wv][t], t);     // teacher-forced
  #pragma unroll 1
  for (int t = TSEQ; t < TOUT; ++t) step(oprev, t);      // autoregressive
}

extern "C" void kernel_launch(void* const* d_in, const int* in_sizes, int n_in,
                              void* d_out, int out_size, void* d_ws, size_t ws_size,
                              hipStream_t stream) {
  const float* x     = (const float*)d_in[0];
  const float* W_ih  = (const float*)d_in[1];
  const float* W_hh  = (const float*)d_in[2];
  const float* b_ih  = (const float*)d_in[3];
  const float* b_hh  = (const float*)d_in[4];
  const float* W_out = (const float*)d_in[5];
  const float* b_out = (const float*)d_in[6];
  float* out = (float*)d_out;

  lstm_seq_kernel<<<BATCH / RPB, 256, 0, stream>>>(
      x, W_ih, W_hh, b_ih, b_hh, W_out, b_out, out);
}